// Round 1
// baseline (145.531 us; speedup 1.0000x reference)
//
#include <hip/hip_runtime.h>
#include <hip/hip_bf16.h>

typedef __bf16 bf16;
typedef __bf16 bf16x8 __attribute__((ext_vector_type(8)));
typedef float f32x4 __attribute__((ext_vector_type(4)));

__device__ __forceinline__ void gload_lds16(const void* g, void* l) {
  __builtin_amdgcn_global_load_lds(
      (const __attribute__((address_space(1))) void*)g,
      (__attribute__((address_space(3))) void*)l, 16, 0, 0);
}

// ---------------------------------------------------------------------------
// C = A[M,K] @ B[N,K]^T   (both row-major, K inner).  bf16 in, f32 accum.
// EPI=0: store f32.  EPI=1: sigmoid -> bf16 store.
// 128x128 tile, BK=32, 256 threads = 4 waves (2x2), 4x4 MFMA 16x16x32 per wave.
// ---------------------------------------------------------------------------
template <int EPI>
__global__ __launch_bounds__(256, 2) void gemm_bt(
    const bf16* __restrict__ A, const bf16* __restrict__ Bw,
    void* __restrict__ C, int M, int N, int K) {
  __shared__ __align__(16) char smem[16384];  // A[128][32] @0, B[128][32] @8192
  const int tid = threadIdx.x;
  const int lane = tid & 63;
  const int wave = tid >> 6;

  const int nb = N >> 7;
  const int nwg = gridDim.x;
  // XCD-aware swizzle (all our grids are divisible by 8)
  const int q8 = nwg >> 3;
  const int tile = (blockIdx.x & 7) * q8 + (blockIdx.x >> 3);
  const int m0 = (tile / nb) << 7;
  const int n0 = (tile % nb) << 7;

  const int wm = (wave >> 1) << 6;
  const int wn = (wave & 1) << 6;

  f32x4 acc[4][4] = {};

  const int r_in = lane >> 2;   // row within 16-row chunk
  const int cch = lane & 3;     // 16B chunk within 64B row

  for (int k0 = 0; k0 < K; k0 += 32) {
    // ---- stage A+B tiles into LDS (16 KB) via global_load_lds width 16 ----
#pragma unroll
    for (int c = 0; c < 4; ++c) {
      const int chunk = wave + (c << 2);         // wave-uniform
      char* ldst = smem + chunk * 1024;
      const bf16* gsrc;
      if (chunk < 8) {
        const int row = m0 + (chunk << 4) + r_in;
        gsrc = A + (size_t)row * K + (k0 + (cch << 3));
      } else {
        const int row = n0 + ((chunk - 8) << 4) + r_in;
        gsrc = Bw + (size_t)row * K + (k0 + (cch << 3));
      }
      gload_lds16(gsrc, ldst);
    }
    __syncthreads();  // drains vmcnt + barrier

    // ---- LDS -> fragments (ds_read_b128) ----
    bf16x8 af[4], bg[4];
    const int lrow = lane & 15;
    const int koff = (lane >> 4) << 4;  // byte offset along K
#pragma unroll
    for (int i = 0; i < 4; ++i) {
      af[i] = *(const bf16x8*)(smem + (wm + (i << 4) + lrow) * 64 + koff);
      bg[i] = *(const bf16x8*)(smem + 8192 + (wn + (i << 4) + lrow) * 64 + koff);
    }
#pragma unroll
    for (int i = 0; i < 4; ++i)
#pragma unroll
      for (int j = 0; j < 4; ++j)
        acc[i][j] =
            __builtin_amdgcn_mfma_f32_16x16x32_bf16(af[i], bg[j], acc[i][j], 0, 0, 0);
    __syncthreads();  // protect LDS before next-tile staging
  }

  // ---- epilogue: C/D layout col=lane&15, row=(lane>>4)*4+reg ----
  const int col0 = n0 + wn + (lane & 15);
  const int rowb = m0 + wm + ((lane >> 4) << 2);
#pragma unroll
  for (int i = 0; i < 4; ++i)
#pragma unroll
    for (int j = 0; j < 4; ++j)
#pragma unroll
      for (int r = 0; r < 4; ++r) {
        const size_t idx = (size_t)(rowb + (i << 4) + r) * N + (col0 + (j << 4));
        const float v = acc[i][j][r];
        if (EPI == 1) {
          const float s = 1.0f / (1.0f + __expf(-v));
          ((bf16*)C)[idx] = (bf16)s;
        } else {
          ((float*)C)[idx] = v;
        }
      }
}

// ---------------------------------------------------------------------------
// Windowed Hamming attention + gate.  One thread per (b,s,h).
// qkv: [8192][3072] bf16 (cols 0..1023 q, 1024..2047 k, 2048..3071 v), already
// sigmoided.  G out: [8192][1024] bf16 gated attention output.
// ---------------------------------------------------------------------------
__global__ __launch_bounds__(256) void rosa_attn(
    const bf16* __restrict__ qkv, const float* __restrict__ emb0,
    const float* __restrict__ emb1, bf16* __restrict__ G) {
  const int t = blockIdx.x * 256 + threadIdx.x;  // 8192*128 threads
  const int row = t >> 7;
  const int h = t & 127;
  const int sp = row & 4095;  // position within sequence (per batch)

  const bf16* qptr = qkv + (size_t)row * 3072 + h * 8;
  bf16x8 qv = *(const bf16x8*)qptr;
  float qb[8], qsum = 0.f;
#pragma unroll
  for (int c = 0; c < 8; ++c) {
    qb[c] = (float)qv[c];
    qsum += qb[c];
  }

  float oacc[8] = {};
  float wsum = 0.f;
  const int wmax = (sp + 1 < 8) ? (sp + 1) : 8;
  const float scale = 0.35355339059327373f;  // 1/sqrt(8)

  for (int d = 0; d < wmax; ++d) {
    const bf16* base = qkv + (size_t)(row - d) * 3072 + h * 8;
    bf16x8 kv = *(const bf16x8*)(base + 1024);
    bf16x8 vv = *(const bf16x8*)(base + 2048);
    float dot = 0.f, ksum = 0.f;
#pragma unroll
    for (int c = 0; c < 8; ++c) {
      const float kb = (float)kv[c];
      dot += qb[c] * kb;
      ksum += kb;
    }
    const float score = (8.0f + 2.0f * dot - qsum - ksum) * scale;  // >= 0
    const float w = __expf(score);                                   // <= e^2.83
    wsum += w;
#pragma unroll
    for (int c = 0; c < 8; ++c) oacc[c] += w * (float)vv[c];
  }

  const float inv = 1.0f / wsum;
  const int e0i = h * 8;
  bf16x8 outv;
#pragma unroll
  for (int c = 0; c < 8; ++c) {
    const float o = oacc[c] * inv;
    const float e0 = emb0[e0i + c], e1 = emb1[e0i + c];
    outv[c] = (bf16)(e0 + (e1 - e0) * o);  // emb1*o + emb0*(1-o)
  }
  *(bf16x8*)(G + (size_t)row * 1024 + h * 8) = outv;
}

// ---------------------------------------------------------------------------
__global__ __launch_bounds__(256) void cvt_f32_bf16(
    const float* __restrict__ src, bf16* __restrict__ dst, int n) {
  const int i = (blockIdx.x * 256 + threadIdx.x) * 8;
  if (i >= n) return;
  const float4 a = *(const float4*)(src + i);
  const float4 b = *(const float4*)(src + i + 4);
  bf16x8 o;
  o[0] = (bf16)a.x; o[1] = (bf16)a.y; o[2] = (bf16)a.z; o[3] = (bf16)a.w;
  o[4] = (bf16)b.x; o[5] = (bf16)b.y; o[6] = (bf16)b.z; o[7] = (bf16)b.w;
  *(bf16x8*)(dst + i) = o;
}

// ---------------------------------------------------------------------------
extern "C" void kernel_launch(void* const* d_in, const int* in_sizes, int n_in,
                              void* d_out, int out_size, void* d_ws,
                              size_t ws_size, hipStream_t stream) {
  const float* X = (const float*)d_in[0];
  const float* Wq = (const float*)d_in[1];
  const float* Wk = (const float*)d_in[2];
  const float* Wv = (const float*)d_in[3];
  const float* Wo = (const float*)d_in[4];
  const float* emb0 = (const float*)d_in[5];
  const float* emb1 = (const float*)d_in[6];

  char* ws = (char*)d_ws;
  bf16* Xb    = (bf16*)(ws + 0);          // 8192*1024          (16 MB)
  bf16* Wqkvb = (bf16*)(ws + 16777216);   // 3072*1024          (6 MB)
  bf16* Wob   = (bf16*)(ws + 23068672);   // 1024*1024          (2 MB)
  bf16* QKVb  = (bf16*)(ws + 25165824);   // 8192*3072          (48 MB)
  bf16* G     = (bf16*)(ws + 75497472);   // 8192*1024          (16 MB)
  float* out  = (float*)d_out;

  // f32 -> bf16 conversions
  cvt_f32_bf16<<<4096, 256, 0, stream>>>(X, Xb, 8388608);
  cvt_f32_bf16<<<512, 256, 0, stream>>>(Wq, Wqkvb, 1048576);
  cvt_f32_bf16<<<512, 256, 0, stream>>>(Wk, Wqkvb + 1048576, 1048576);
  cvt_f32_bf16<<<512, 256, 0, stream>>>(Wv, Wqkvb + 2097152, 1048576);
  cvt_f32_bf16<<<512, 256, 0, stream>>>(Wo, Wob, 1048576);

  // fused QKV projection + sigmoid -> bf16
  gemm_bt<1><<<64 * 24, 256, 0, stream>>>(Xb, Wqkvb, QKVb, 8192, 3072, 1024);

  // windowed attention + gate -> bf16
  rosa_attn<<<4096, 256, 0, stream>>>(QKVb, emb0, emb1, G);

  // output projection -> f32
  gemm_bt<0><<<64 * 8, 256, 0, stream>>>(G, Wob, out, 8192, 1024, 1024);
}